// Round 18
// baseline (15118.465 us; speedup 1.0000x reference)
//
#include <hip/hip_runtime.h>

#define NPTS 8192
#define N2 (NPTS * 2)
#define NCH 16             // j-chunks for big matvec
#define JCH (NPTS / NCH)   // 512
#define ITILE 256          // i-rows per matvec block
#define NIT (NPTS / ITILE) // 32
#define NBLK1 (NIT * NCH)  // 512 matvec blocks
#define IB 8
#define NJS 16             // j-slices in matvec
#define JPT (JCH / NJS)    // 32
#define NUG 1.0e-4
#define INVNUG 1.0e4
#define DELTA 1.0e-2
#define LAM 1.0e-5

#if __has_builtin(__builtin_amdgcn_exp2f)
#define EXP2F(x) __builtin_amdgcn_exp2f(x)
#else
#define EXP2F(x) __expf(0.6931471805599453f * (x))
#endif

// ---------------- setup: scaled coords, f64 CG state ----------------
extern "C" __global__ void __launch_bounds__(256)
k_setup(const float* __restrict__ Xmu, const float* __restrict__ Yeta,
        const float* __restrict__ Ymu, const float* __restrict__ Z,
        float4* __restrict__ U4, float4* __restrict__ W4, float* __restrict__ NS,
        float4* __restrict__ M4, float4* __restrict__ Y4,
        float2* __restrict__ Pf0, float2* __restrict__ Pf1,
        double* __restrict__ r64, double* __restrict__ x64)
{
  const float c2 = 0.84932180028802f;        // 1/sqrt(2 ln 2)
  int tid = threadIdx.x;
  int idx = blockIdx.x * 256 + tid;          // 64 blocks -> 16384
  int i = idx >> 1;
  r64[idx] = (double)Z[idx];
  x64[idx] = 0.0;
  if ((idx & 1) == 0) {
    float a0 = Xmu[2 * i], a1 = Xmu[2 * i + 1];
    float e0 = Yeta[2 * i], e1 = Yeta[2 * i + 1];
    float m0 = Ymu[2 * i], m1 = Ymu[2 * i + 1];
    float z0 = Z[2 * i], z1 = Z[2 * i + 1];
    float u0 = c2 * a0, u1 = c2 * a1, u2 = c2 * e0, u3 = c2 * e1;
    float n = fmaf(u3, u3, fmaf(u2, u2, fmaf(u1, u1, u0 * u0)));
    U4[i] = make_float4(u0, u1, u2, u3);
    W4[i] = make_float4(2.f * u0, 2.f * u1, 2.f * u2, 2.f * u3);
    NS[i] = n;
    M4[i] = make_float4(a0, a1, e0 + z0, e1 + z1);
    Y4[i] = make_float4(a0, a1, m0, m1);
    Pf0[i] = make_float2(0.f, 0.f);
    Pf1[i] = make_float2(0.f, 0.f);
  }
}

// ---------------- MMD: three fused Gram sums ----------------
#define MTPB 256
#define MCHK 1024
extern "C" __global__ void __launch_bounds__(MTPB)
k_mmd(const float4* __restrict__ M4, const float4* __restrict__ Y4,
      double* __restrict__ mmdpart)
{
  __shared__ float4 sM[MCHK];
  __shared__ float4 sY[MCHK];
  __shared__ double sred[MTPB];
  int tid = threadIdx.x;
  int blk = blockIdx.x;
  int itile = blk >> 3;
  int ch = blk & 7;
  int j0 = ch * MCHK;
  for (int u = tid; u < MCHK; u += MTPB) {
    sM[u] = M4[j0 + u];
    sY[u] = Y4[j0 + u];
  }
  __syncthreads();
  int i = itile * MTPB + tid;
  float4 mi = M4[i];
  float4 yi = Y4[i];
  double szz = 0.0, szy = 0.0, syy = 0.0;
  for (int jj = 0; jj < MCHK; ++jj) {
    float4 mj = sM[jj];
    float4 yj = sY[jj];
    float d0 = mi.x - mj.x, d1 = mi.y - mj.y;
    float a = fmaf(d1, d1, d0 * d0);
    float u0 = mi.z - mj.z, u1 = mi.w - mj.w;
    float v0 = mi.z - yj.z, v1 = mi.w - yj.w;
    float w0 = yi.z - yj.z, w1 = yi.w - yj.w;
    float dzz = fmaf(u0, u0, fmaf(u1, u1, a));
    float dzy = fmaf(v0, v0, fmaf(v1, v1, a));
    float dyy = fmaf(w0, w0, fmaf(w1, w1, a));
    szz += (double)__expf(-0.5f * dzz);
    szy += (double)__expf(-0.5f * dzy);
    syy += (double)__expf(-0.5f * dyy);
  }
  double v[3] = {szz, szy, syy};
  for (int k = 0; k < 3; ++k) {
    sred[tid] = v[k];
    __syncthreads();
    for (int st = MTPB >> 1; st >= 1; st >>= 1) {
      if (tid < st) sred[tid] += sred[tid + st];
      __syncthreads();
    }
    if (tid == 0) mmdpart[blk * 3 + k] = sred[0];
    __syncthreads();
  }
}

__device__ __forceinline__ float evalK(float4 u, float nu, float4 ws, float nss) {
  float tt = fmaf(u.x, ws.x, fmaf(u.y, ws.y, fmaf(u.z, ws.z, u.w * ws.w)));
  return EXP2F(tt - nu - nss);
}

// ---------------- G = delta I + eta W + C^T C (f64), templated on rank M ----
template<int M>
__global__ void __launch_bounds__(256)
k_gbuild(const float4* __restrict__ U4, const float4* __restrict__ W4,
         const float* __restrict__ NS, double* __restrict__ G)
{
  constexpr int SS = NPTS / M;
  __shared__ float ea[8][32];
  __shared__ float eb[8][32];
  int tid = threadIdx.x;
  int blk = blockIdx.x;
  int a0 = (blk / (M / 32)) * 32;
  int b0 = (blk % (M / 32)) * 32;
  int arow = tid >> 5;           // 0..7
  int bl = tid & 31;             // 0..31
  int sa = (a0 + bl) * SS;
  int sb = (b0 + bl) * SS;
  float4 wsa = W4[sa]; float nsa = NS[sa];
  float4 wsb = W4[sb]; float nsb = NS[sb];
  double acc[4] = {0.0, 0.0, 0.0, 0.0};
  for (int ic = 0; ic < NPTS / 8; ++ic) {
    int i = ic * 8 + arow;
    float4 u = U4[i];
    float nu = NS[i];
    ea[arow][bl] = evalK(u, nu, wsa, nsa);
    eb[arow][bl] = evalK(u, nu, wsb, nsb);
    __syncthreads();
#pragma unroll
    for (int kk = 0; kk < 4; ++kk) {
      int al = (tid >> 5) + 8 * kk;
      double s = 0.0;
#pragma unroll
      for (int ii = 0; ii < 8; ++ii)
        s += (double)ea[ii][al] * (double)eb[ii][bl];
      acc[kk] += s;
    }
    __syncthreads();
  }
#pragma unroll
  for (int kk = 0; kk < 4; ++kk) {
    int al = (tid >> 5) + 8 * kk;
    int a = a0 + al, b = b0 + bl;
    int ia = a * SS;
    float4 ua = U4[ia];
    float na = NS[ia];
    double w_ab = (double)evalK(ua, na, wsb, nsb);   // K(S_a, S_b)
    double g = acc[kk] + NUG * w_ab + ((a == b) ? DELTA : 0.0);
    G[(size_t)a * M + b] = g;
  }
}

// ---------------- block Gauss-Jordan: 16 pivots per launch (ping-pong, f64) ----
// M/8 blocks x M threads; block owns 8 rows; every block redundantly inverts
// the 16x16 panel in LDS and computes W = Pinv*R; elimination order matches
// the scalar pivot sequence.
template<int M>
__global__ void __launch_bounds__(1024)
k_gjpanel(const double* __restrict__ Mc, double* __restrict__ Mn, int k0)
{
  __shared__ double pm[16][16];
  __shared__ double sW[16][M];              // 64 / 128 KB
  __shared__ double cl[8][16];
  __shared__ double trow[16], tcol[16];
  __shared__ double ps;
  int tid = threadIdx.x;
  int blk = blockIdx.x;

  if (tid < 256)
    pm[tid >> 4][tid & 15] = Mc[(size_t)(k0 + (tid >> 4)) * M + k0 + (tid & 15)];
  __syncthreads();
  for (int piv = 0; piv < 16; ++piv) {
    if (tid == 0) ps = 1.0 / pm[piv][piv];
    if (tid < 16) { trow[tid] = pm[piv][tid]; tcol[tid] = pm[tid][piv]; }
    __syncthreads();
    double p = ps;
    if (tid < 256) {
      int r = tid >> 4, c = tid & 15;
      double v;
      if (r == piv && c == piv) v = p;
      else if (r == piv)        v = trow[c] * p;
      else if (c == piv)        v = -tcol[r] * p;
      else                      v = fma(-tcol[r] * p, trow[c], pm[r][c]);
      pm[r][c] = v;
    }
    __syncthreads();
  }
  {
    double m[16];
#pragma unroll
    for (int s = 0; s < 16; ++s) m[s] = Mc[(size_t)(k0 + s) * M + tid];
#pragma unroll
    for (int r = 0; r < 16; ++r) {
      double acc = 0.0;
#pragma unroll
      for (int s = 0; s < 16; ++s) acc = fma(pm[r][s], m[s], acc);
      sW[r][tid] = acc;
    }
  }
  if (tid < 128)
    cl[tid >> 4][tid & 15] = Mc[(size_t)(blk * 8 + (tid >> 4)) * M + k0 + (tid & 15)];
  __syncthreads();

  int jk = tid - k0;
  bool inK = (jk >= 0 && jk < 16);
#pragma unroll
  for (int rr = 0; rr < 8; ++rr) {
    int i = blk * 8 + rr;
    int pr = i - k0;
    double v;
    if (pr >= 0 && pr < 16) {                // panel-owner row
      v = inK ? pm[pr][jk] : sW[pr][tid];
    } else if (inK) {
      double acc = 0.0;
#pragma unroll
      for (int s = 0; s < 16; ++s) acc = fma(cl[rr][s], pm[s][jk], acc);
      v = -acc;
    } else {
      double acc = Mc[(size_t)i * M + tid];
#pragma unroll
      for (int s = 0; s < 16; ++s) acc = fma(-cl[rr][s], sW[s][tid], acc);
      v = acc;
    }
    Mn[(size_t)i * M + tid] = v;
  }
}

// ---------------- D = C * Ginv (f32 out, f64 accum); 512 blocks x M thr ------
template<int M>
__global__ void __launch_bounds__(1024)
k_dbuild(const float4* __restrict__ U4, const float4* __restrict__ W4,
         const float* __restrict__ NS, const double* __restrict__ Ginv,
         float* __restrict__ D)
{
  constexpr int SS = NPTS / M;
  __shared__ float sc[16][M];                // 32 / 64 KB
  __shared__ float4 su[16];
  __shared__ float snl[16];
  int tid = threadIdx.x;
  int blk = blockIdx.x;
  int i0 = blk * 16;
  if (tid < 16) { su[tid] = U4[i0 + tid]; snl[tid] = NS[i0 + tid]; }
  __syncthreads();
  {
    int si = tid * SS;
    float4 ws = W4[si];
    float nss = NS[si];
#pragma unroll
    for (int r = 0; r < 16; ++r)
      sc[r][tid] = evalK(su[r], snl[r], ws, nss);
  }
  __syncthreads();
  double acc[16];
#pragma unroll
  for (int r = 0; r < 16; ++r) acc[r] = 0.0;
  for (int k = 0; k < M; ++k) {
    double g = Ginv[(size_t)k * M + tid];     // coalesced
#pragma unroll
    for (int r = 0; r < 16; ++r)
      acc[r] = fma((double)sc[r][k], g, acc[r]);   // LDS broadcast
  }
#pragma unroll
  for (int r = 0; r < 16; ++r)
    D[(size_t)(i0 + r) * M + tid] = (float)acc[r];
}

// ---------------- K1: big matvec q = K p (+eta p), p = z + beta p ----------------
extern "C" __global__ void __launch_bounds__(512, 4)
k_matvec(const float4* __restrict__ U4, const float4* __restrict__ W4,
         const float* __restrict__ NS,
         const float2* __restrict__ Zv, const float2* __restrict__ Pfp,
         float2* __restrict__ Pfc, float2* __restrict__ qpart,
         double* __restrict__ pqpart, const double* __restrict__ rhopart, int t)
{
  __shared__ float4 sw[JCH];
  __shared__ float4 sa[JCH];
  __shared__ double s1[512], s2[512];
  __shared__ double sc[2];
  int tid = threadIdx.x;
  int blk = blockIdx.x;
  int it = blk >> 4;
  int ch = blk & (NCH - 1);
  int j = ch * JCH + tid;

  float4 wj = W4[j];
  float nj = NS[j];
  float2 zj = Zv[j];
  float2 pj = Pfp[j];

  // beta = rho_{t-1} / rho_{t-2}
  if (t == 1) {
    if (tid < 2) sc[tid] = 0.0;
    __syncthreads();
  } else {
    const double* cur = rhopart + ((t - 1) & 1) * 128;
    const double* prv = rhopart + ((t - 2) & 1) * 128;
    if (tid < 128) { s1[tid] = cur[tid]; s2[tid] = prv[tid]; }
    __syncthreads();
    for (int st = 64; st >= 2; st >>= 1) {
      if (tid < st) { s1[tid] += s1[tid + st]; s2[tid] += s2[tid + st]; }
      __syncthreads();
    }
    if (tid < 2) sc[tid] = s1[tid] / s2[tid];
    __syncthreads();
  }
  float b0 = (float)sc[0], b1 = (float)sc[1];

  sw[tid] = wj;
  sa[tid] = make_float4(nj, fmaf(b0, pj.x, zj.x), fmaf(b1, pj.y, zj.y), 0.f);
  __syncthreads();

  int js = tid & (NJS - 1);
  int ig = tid >> 4;
  int i0 = it * ITILE + ig * IB;
  float4 ui[IB];
  float ni[IB];
#pragma unroll
  for (int k = 0; k < IB; ++k) { ui[k] = U4[i0 + k]; ni[k] = NS[i0 + k]; }
  float qa0[IB], qa1[IB];
#pragma unroll
  for (int k = 0; k < IB; ++k) { qa0[k] = 0.f; qa1[k] = 0.f; }
#pragma unroll 4
  for (int jj = 0; jj < JPT; ++jj) {
    int jl = jj * NJS + js;
    float4 w = sw[jl];
    float4 aa = sa[jl];
#pragma unroll
    for (int k = 0; k < IB; ++k) {
      float ttn = -(ni[k] + aa.x);
      ttn = fmaf(ui[k].x, w.x, ttn);
      ttn = fmaf(ui[k].y, w.y, ttn);
      ttn = fmaf(ui[k].z, w.z, ttn);
      ttn = fmaf(ui[k].w, w.w, ttn);
      float e = EXP2F(ttn);
      qa0[k] = fmaf(e, aa.y, qa0[k]);
      qa1[k] = fmaf(e, aa.z, qa1[k]);
    }
  }
#pragma unroll
  for (int k = 0; k < IB; ++k) {
#pragma unroll
    for (int d = 8; d >= 1; d >>= 1) {
      qa0[k] += __shfl_down(qa0[k], (unsigned)d, 16);
      qa1[k] += __shfl_down(qa1[k], (unsigned)d, 16);
    }
  }
  double pq0 = 0.0, pq1 = 0.0;
  if (js == 0) {
    int owner = (it & (NCH - 1));
#pragma unroll
    for (int k = 0; k < IB; ++k) {
      int i = i0 + k;
      float2 zi = Zv[i];
      float2 pi = Pfp[i];
      float pn0 = fmaf(b0, pi.x, zi.x);
      float pn1 = fmaf(b1, pi.y, zi.y);
      qpart[(size_t)ch * NPTS + i] = make_float2(qa0[k], qa1[k]);
      if (ch == owner) Pfc[i] = make_float2(pn0, pn1);
      pq0 += (double)pn0 * (double)qa0[k];
      pq1 += (double)pn1 * (double)qa1[k];
      if (ch == 0) {
        pq0 += NUG * (double)pn0 * (double)pn0;
        pq1 += NUG * (double)pn1 * (double)pn1;
      }
    }
  }
  s1[tid] = pq0;
  s2[tid] = pq1;
  __syncthreads();
  for (int st = 256; st >= 1; st >>= 1) {
    if (tid < st) { s1[tid] += s1[tid + st]; s2[tid] += s2[tid + st]; }
    __syncthreads();
  }
  if (tid == 0) { pqpart[blk * 2 + 0] = s1[0]; pqpart[blk * 2 + 1] = s2[0]; }
}

// ---------------- K2: alpha, x/r update, y1 = C^T r partials ----------------
template<int M>
__global__ void __launch_bounds__(256)
k_update(const float* __restrict__ qpartf, const float2* __restrict__ Pfc,
         double* __restrict__ r64, double* __restrict__ x64,
         const float4* __restrict__ U4, const float4* __restrict__ W4,
         const float* __restrict__ NS,
         const double* __restrict__ pqpart, const double* __restrict__ rhopart,
         double* __restrict__ y1part, int t)
{
  constexpr int SS = NPTS / M;
  __shared__ double s1[256];
  __shared__ double s2[128];
  __shared__ double alpha2[2];
  __shared__ float4 su[128];
  __shared__ float snl[128];
  __shared__ double rl[2][128];
  int tid = threadIdx.x;
  int blk = blockIdx.x;
  int idx = blk * 256 + tid;
  double rv;
  if (t > 0) {
    s1[tid] = pqpart[tid] + pqpart[tid + 256] + pqpart[tid + 512] + pqpart[tid + 768];
    if (tid < 128) s2[tid] = rhopart[((t - 1) & 1) * 128 + tid];
    __syncthreads();
    for (int st = 128; st >= 2; st >>= 1) {
      if (tid < st) s1[tid] += s1[tid + st];
      if (st <= 64 && tid < st) s2[tid] += s2[tid + st];
      __syncthreads();
    }
    if (tid < 2) alpha2[tid] = s2[tid] / s1[tid];
    __syncthreads();
    double a = alpha2[idx & 1];
    float pn = ((const float*)Pfc)[idx];
    double q = 0.0;
#pragma unroll
    for (int c = 0; c < NCH; ++c) q += (double)qpartf[(size_t)c * N2 + idx];
    q = fma((double)NUG, (double)pn, q);
    rv = fma(-a, q, r64[idx]);
    x64[idx] = fma(a, (double)pn, x64[idx]);
    r64[idx] = rv;
  } else {
    rv = r64[idx];
  }
  rl[idx & 1][tid >> 1] = rv;
  if (tid < 128) {
    su[tid] = U4[blk * 128 + tid];
    snl[tid] = NS[blk * 128 + tid];
  }
  __syncthreads();
  // y1 partials: this block's 128-row slice against all M samples
  for (int rr = 0; rr < M / 256; ++rr) {
    int s = rr * 256 + tid;
    int si = s * SS;
    float4 ws = W4[si];
    float nss = NS[si];
    double y0 = 0.0, y1v = 0.0;
#pragma unroll 4
    for (int il = 0; il < 128; ++il) {
      float4 u = su[il];
      float tt = fmaf(u.x, ws.x, fmaf(u.y, ws.y, fmaf(u.z, ws.z, u.w * ws.w)));
      float e = EXP2F(tt - snl[il] - nss);
      y0 = fma((double)e, rl[0][il], y0);
      y1v = fma((double)e, rl[1][il], y1v);
    }
    y1part[(size_t)s * 128 + blk * 2 + 0] = y0;
    y1part[(size_t)s * 128 + blk * 2 + 1] = y1v;
  }
}

// ---------------- K3 (D path): z = (r - D y1)/eta ; rho partials ----------------
template<int M>
__global__ void __launch_bounds__(256)
k_dz(const double* __restrict__ r64, const double* __restrict__ y1part,
     const float* __restrict__ D, float2* __restrict__ Zv,
     double* __restrict__ rhopart, int t)
{
  __shared__ double ly1[M][2];
  __shared__ double zl[128][2];
  __shared__ double s1[256], s2[256];
  int tid = threadIdx.x;
  int blk = blockIdx.x;
  for (int s = tid; s < M; s += 256) {
    const double* base = y1part + (size_t)s * 128;
    double a0 = 0.0, a1 = 0.0;
#pragma unroll 8
    for (int b = 0; b < 64; ++b) { a0 += base[2 * b]; a1 += base[2 * b + 1]; }
    ly1[s][0] = a0; ly1[s][1] = a1;
  }
  __syncthreads();
  {
    int lane = tid & 63, wv = tid >> 6;      // 4 waves
    for (int rnd = 0; rnd < 32; ++rnd) {
      int pt = wv * 32 + rnd;
      const float* drow = D + (size_t)(blk * 128 + pt) * M;
      double a0 = 0.0, a1 = 0.0;
#pragma unroll
      for (int m = 0; m < M / 64; ++m) {
        int s = lane + 64 * m;               // coalesced across lanes
        double dv = (double)drow[s];
        a0 = fma(dv, ly1[s][0], a0);
        a1 = fma(dv, ly1[s][1], a1);
      }
#pragma unroll
      for (int d = 32; d >= 1; d >>= 1) {
        a0 += __shfl_down(a0, (unsigned)d, 64);
        a1 += __shfl_down(a1, (unsigned)d, 64);
      }
      if (lane == 0) { zl[pt][0] = a0; zl[pt][1] = a1; }
    }
  }
  __syncthreads();
  double rz0 = 0.0, rz1 = 0.0;
  if (tid < 128) {
    int i = blk * 128 + tid;
    double r0 = r64[2 * i], r1 = r64[2 * i + 1];
    double z0 = (r0 - zl[tid][0]) * INVNUG;
    double z1 = (r1 - zl[tid][1]) * INVNUG;
    Zv[i] = make_float2((float)z0, (float)z1);
    rz0 = r0 * z0;
    rz1 = r1 * z1;
  }
  s1[tid] = rz0;
  s2[tid] = rz1;
  __syncthreads();
  for (int st = 128; st >= 1; st >>= 1) {
    if (tid < st) { s1[tid] += s1[tid + st]; s2[tid] += s2[tid + st]; }
    __syncthreads();
  }
  if (tid == 0) {
    rhopart[(t & 1) * 128 + blk * 2 + 0] = s1[0];
    rhopart[(t & 1) * 128 + blk * 2 + 1] = s2[0];
  }
}

// ---------------- K34 fallback (no-D path) ----------------
template<int M>
__global__ void __launch_bounds__(256)
k_y2z(const float4* __restrict__ U4, const float4* __restrict__ W4,
      const float* __restrict__ NS, const double* __restrict__ r64,
      const double* __restrict__ y1part, const double* __restrict__ Ginv,
      float2* __restrict__ Zv, double* __restrict__ rhopart, int t)
{
  constexpr int SS = NPTS / M;
  __shared__ double ly1[M][2];
  __shared__ double ly2[M][2];
  __shared__ double s1[256], s2[256];
  int tid = threadIdx.x;
  int blk = blockIdx.x;
  for (int s = tid; s < M; s += 256) {
    const double* base = y1part + (size_t)s * 128;
    double a0 = 0.0, a1 = 0.0;
#pragma unroll 8
    for (int b = 0; b < 64; ++b) { a0 += base[2 * b]; a1 += base[2 * b + 1]; }
    ly1[s][0] = a0; ly1[s][1] = a1;
  }
  __syncthreads();
  {
    int g = tid >> 5, l = tid & 31;
    for (int ss = 0; ss < M / 8; ++ss) {
      int so = g * (M / 8) + ss;
      const double* grow = Ginv + (size_t)so * M;
      double c0 = 0.0, c1 = 0.0;
#pragma unroll
      for (int m = 0; m < M / 32; ++m) {
        int jj = m * 32 + l;
        double gv = grow[jj];
        c0 = fma(gv, ly1[jj][0], c0);
        c1 = fma(gv, ly1[jj][1], c1);
      }
#pragma unroll
      for (int d = 16; d >= 1; d >>= 1) {
        c0 += __shfl_down(c0, (unsigned)d, 32);
        c1 += __shfl_down(c1, (unsigned)d, 32);
      }
      if (l == 0) { ly2[so][0] = c0; ly2[so][1] = c1; }
    }
  }
  __syncthreads();
  int pt = tid & 127;
  int half = tid >> 7;
  int i = blk * 128 + pt;
  float4 u = U4[i];
  float nu = NS[i];
  double acc0 = 0.0, acc1 = 0.0;
  int sbase = half * (M / 2);
#pragma unroll 4
  for (int s = 0; s < M / 2; ++s) {
    int so = sbase + s;
    int si = so * SS;
    float4 ws = W4[si];
    float nss = NS[si];
    float tt = fmaf(u.x, ws.x, fmaf(u.y, ws.y, fmaf(u.z, ws.z, u.w * ws.w)));
    float e = EXP2F(tt - nu - nss);
    acc0 = fma((double)e, ly2[so][0], acc0);
    acc1 = fma((double)e, ly2[so][1], acc1);
  }
  s1[tid] = acc0;
  s2[tid] = acc1;
  __syncthreads();
  double rz0 = 0.0, rz1 = 0.0;
  if (tid < 128) {
    double a0 = s1[tid] + s1[tid + 128];
    double a1 = s2[tid] + s2[tid + 128];
    double r0 = r64[2 * i], r1 = r64[2 * i + 1];
    double z0 = (r0 - a0) * INVNUG;
    double z1 = (r1 - a1) * INVNUG;
    Zv[i] = make_float2((float)z0, (float)z1);
    rz0 = r0 * z0;
    rz1 = r1 * z1;
  }
  __syncthreads();
  s1[tid] = rz0;
  s2[tid] = rz1;
  __syncthreads();
  for (int st = 128; st >= 1; st >>= 1) {
    if (tid < st) { s1[tid] += s1[tid + st]; s2[tid] += s2[tid + st]; }
    __syncthreads();
  }
  if (tid == 0) {
    rhopart[(t & 1) * 128 + blk * 2 + 0] = s1[0];
    rhopart[(t & 1) * 128 + blk * 2 + 1] = s2[0];
  }
}

// ---------------- final combine ----------------
extern "C" __global__ void __launch_bounds__(256)
k_final(const float* __restrict__ Z, const double* __restrict__ x64,
        const double* __restrict__ mmdpart, float* __restrict__ out)
{
  __shared__ double sred[256];
  int tid = threadIdx.x;
  double zx = 0.0;
  for (int idx = tid; idx < N2; idx += 256)
    zx += (double)Z[idx] * x64[idx];
  double acc[4];
  acc[0] = zx;
  acc[1] = mmdpart[tid * 3 + 0];
  acc[2] = mmdpart[tid * 3 + 1];
  acc[3] = mmdpart[tid * 3 + 2];
  double tot[4];
  for (int k = 0; k < 4; ++k) {
    sred[tid] = acc[k];
    __syncthreads();
    for (int st = 128; st >= 1; st >>= 1) {
      if (tid < st) sred[tid] += sred[tid + st];
      __syncthreads();
    }
    tot[k] = sred[0];
    __syncthreads();
  }
  if (tid == 0) {
    double nn = (double)NPTS * (double)NPTS;
    double mmd = (tot[1] - 2.0 * tot[2] + tot[3]) / nn;
    out[0] = (float)(mmd + LAM * tot[0]);
  }
}

template<int M>
static void run_pcg(const float4* U4, const float4* W4, const float* NS,
                    const float* Z, float2* Zv, float2* Pf0, float2* Pf1,
                    double* r64, double* x64, float2* qpart, double* pqpart,
                    double* rhopart, double* y1part, double* Gb0, double* Gb1,
                    float* D, int useD, int T, hipStream_t stream)
{
  hipLaunchKernelGGL((k_gbuild<M>), dim3((M / 32) * (M / 32)), dim3(256), 0,
                     stream, U4, W4, NS, Gb0);
  for (int p = 0; p < M / 16; ++p) {
    double* Mc = (p & 1) ? Gb1 : Gb0;
    double* Mn = (p & 1) ? Gb0 : Gb1;
    hipLaunchKernelGGL((k_gjpanel<M>), dim3(M / 8), dim3(M), 0, stream,
                       Mc, Mn, p * 16);
  }
  double* Ginv = Gb0;                        // M/16 even -> result in Gb0
  if (useD)
    hipLaunchKernelGGL((k_dbuild<M>), dim3(512), dim3(M), 0, stream,
                       U4, W4, NS, Ginv, D);

  float2* Pf[2] = { Pf0, Pf1 };
  hipLaunchKernelGGL((k_update<M>), dim3(64), dim3(256), 0, stream,
                     (const float*)qpart, Pf[0], r64, x64, U4, W4, NS,
                     pqpart, rhopart, y1part, 0);
  if (useD)
    hipLaunchKernelGGL((k_dz<M>), dim3(64), dim3(256), 0, stream,
                       r64, y1part, D, Zv, rhopart, 0);
  else
    hipLaunchKernelGGL((k_y2z<M>), dim3(64), dim3(256), 0, stream,
                       U4, W4, NS, r64, y1part, Ginv, Zv, rhopart, 0);

  for (int t = 1; t <= T; ++t) {
    float2* Pprev = Pf[(t - 1) & 1];
    float2* Pcur  = Pf[t & 1];
    hipLaunchKernelGGL(k_matvec, dim3(NBLK1), dim3(512), 0, stream,
                       U4, W4, NS, Zv, Pprev, Pcur, qpart, pqpart, rhopart, t);
    hipLaunchKernelGGL((k_update<M>), dim3(64), dim3(256), 0, stream,
                       (const float*)qpart, Pcur, r64, x64, U4, W4, NS,
                       pqpart, rhopart, y1part, t);
    if (t < T) {
      if (useD)
        hipLaunchKernelGGL((k_dz<M>), dim3(64), dim3(256), 0, stream,
                           r64, y1part, D, Zv, rhopart, t);
      else
        hipLaunchKernelGGL((k_y2z<M>), dim3(64), dim3(256), 0, stream,
                           U4, W4, NS, r64, y1part, Ginv, Zv, rhopart, t);
    }
  }
}

extern "C" void kernel_launch(void* const* d_in, const int* in_sizes, int n_in,
                              void* d_out, int out_size, void* d_ws, size_t ws_size,
                              hipStream_t stream)
{
  (void)in_sizes; (void)n_in; (void)out_size;
  const float* Xmu  = (const float*)d_in[0];
  const float* Yeta = (const float*)d_in[1];
  const float* Ymu  = (const float*)d_in[2];
  const float* Z    = (const float*)d_in[3];
  float* out = (float*)d_out;

  char* w = (char*)d_ws;
  float4* U4      = (float4*)(w);                      // 128K
  float4* W4      = (float4*)(w + (128 << 10));        // 128K
  float*  NS      = (float*)(w + (256 << 10));         // 32K
  float4* M4      = (float4*)(w + (288 << 10));        // 128K
  float4* Y4      = (float4*)(w + (416 << 10));        // 128K
  float2* Zv      = (float2*)(w + (544 << 10));        // 64K
  float2* Pf0     = (float2*)(w + (608 << 10));        // 64K
  float2* Pf1     = (float2*)(w + (672 << 10));        // 64K
  double* r64     = (double*)(w + (736 << 10));        // 128K
  double* x64     = (double*)(w + (864 << 10));        // 128K
  float2* qpart   = (float2*)(w + (992 << 10));        // 1M
  double* pqpart  = (double*)(w + (2016 << 10));       // 8K
  double* rhopart = (double*)(w + (2024 << 10));       // 2K
  double* mmdpart = (double*)(w + (2026 << 10));       // 6K
  double* y1part  = (double*)(w + (2032 << 10));       // m*128*8 (512K or 1M)

  // runtime path choice by workspace size
  // need(m) = 2032K + m*128*8 + 2*m*m*8 + 8192*m*4
  size_t need1024 = ((size_t)2032 << 10) + ((size_t)1024 * 128 * 8)
                  + 2 * ((size_t)1024 * 1024 * 8) + ((size_t)8192 * 1024 * 4);
  size_t need512  = ((size_t)2032 << 10) + ((size_t)512 * 128 * 8)
                  + 2 * ((size_t)512 * 512 * 8) + ((size_t)8192 * 512 * 4);
  size_t need512noD = ((size_t)2032 << 10) + ((size_t)512 * 128 * 8)
                  + 2 * ((size_t)512 * 512 * 8);

  int m, T, useD;
  if (ws_size >= need1024)      { m = 1024; T = 120; useD = 1; }
  else if (ws_size >= need512)  { m = 512;  T = 144; useD = 1; }
  else                          { m = 512;  T = 144; useD = 0; (void)need512noD; }

  size_t p = ((size_t)2032 << 10) + (size_t)m * 128 * 8;
  double* Gb0 = (double*)(w + p);  p += (size_t)m * m * 8;
  double* Gb1 = (double*)(w + p);  p += (size_t)m * m * 8;
  float*  D   = (float*)(w + p);

  hipLaunchKernelGGL(k_setup, dim3(64), dim3(256), 0, stream,
                     Xmu, Yeta, Ymu, Z, U4, W4, NS, M4, Y4,
                     Pf0, Pf1, r64, x64);
  hipLaunchKernelGGL(k_mmd, dim3(256), dim3(MTPB), 0, stream, M4, Y4, mmdpart);

  if (m == 1024)
    run_pcg<1024>(U4, W4, NS, Z, Zv, Pf0, Pf1, r64, x64, qpart, pqpart,
                  rhopart, y1part, Gb0, Gb1, D, useD, T, stream);
  else
    run_pcg<512>(U4, W4, NS, Z, Zv, Pf0, Pf1, r64, x64, qpart, pqpart,
                 rhopart, y1part, Gb0, Gb1, D, useD, T, stream);

  hipLaunchKernelGGL(k_final, dim3(1), dim3(256), 0, stream,
                     Z, x64, mmdpart, out);
}

// Round 19
// 10510.139 us; speedup vs baseline: 1.4385x; 1.4385x over previous
//
#include <hip/hip_runtime.h>

#define NPTS 8192
#define N2 (NPTS * 2)
#define NCH 16             // j-chunks for big matvec
#define JCH (NPTS / NCH)   // 512
#define ITILE 256          // i-rows per matvec block
#define NIT (NPTS / ITILE) // 32
#define NBLK1 (NIT * NCH)  // 512 matvec blocks
#define IB 8
#define NJS 16             // j-slices in matvec
#define JPT (JCH / NJS)    // 32
#define MNY 512            // Nystrom rank
#define SSTR 16            // landmark stride
#define T_ITERS 136
#define NUG 1.0e-4
#define INVNUG 1.0e4
#define DELTA 1.0e-2
#define LAM 1.0e-5

#if __has_builtin(__builtin_amdgcn_exp2f)
#define EXP2F(x) __builtin_amdgcn_exp2f(x)
#else
#define EXP2F(x) __expf(0.6931471805599453f * (x))
#endif

// ---------------- setup: scaled coords, f64 CG state ----------------
extern "C" __global__ void __launch_bounds__(256)
k_setup(const float* __restrict__ Xmu, const float* __restrict__ Yeta,
        const float* __restrict__ Ymu, const float* __restrict__ Z,
        float4* __restrict__ U4, float4* __restrict__ W4, float* __restrict__ NS,
        float4* __restrict__ M4, float4* __restrict__ Y4,
        float2* __restrict__ Pf0, float2* __restrict__ Pf1,
        double* __restrict__ r64, double* __restrict__ x64)
{
  const float c2 = 0.84932180028802f;        // 1/sqrt(2 ln 2)
  int tid = threadIdx.x;
  int idx = blockIdx.x * 256 + tid;          // 64 blocks -> 16384
  int i = idx >> 1;
  r64[idx] = (double)Z[idx];
  x64[idx] = 0.0;
  if ((idx & 1) == 0) {
    float a0 = Xmu[2 * i], a1 = Xmu[2 * i + 1];
    float e0 = Yeta[2 * i], e1 = Yeta[2 * i + 1];
    float m0 = Ymu[2 * i], m1 = Ymu[2 * i + 1];
    float z0 = Z[2 * i], z1 = Z[2 * i + 1];
    float u0 = c2 * a0, u1 = c2 * a1, u2 = c2 * e0, u3 = c2 * e1;
    float n = fmaf(u3, u3, fmaf(u2, u2, fmaf(u1, u1, u0 * u0)));
    U4[i] = make_float4(u0, u1, u2, u3);
    W4[i] = make_float4(2.f * u0, 2.f * u1, 2.f * u2, 2.f * u3);
    NS[i] = n;
    M4[i] = make_float4(a0, a1, e0 + z0, e1 + z1);
    Y4[i] = make_float4(a0, a1, m0, m1);
    Pf0[i] = make_float2(0.f, 0.f);
    Pf1[i] = make_float2(0.f, 0.f);
  }
}

// ---------------- MMD: three fused Gram sums ----------------
#define MTPB 256
#define MCHK 1024
extern "C" __global__ void __launch_bounds__(MTPB)
k_mmd(const float4* __restrict__ M4, const float4* __restrict__ Y4,
      double* __restrict__ mmdpart)
{
  __shared__ float4 sM[MCHK];
  __shared__ float4 sY[MCHK];
  __shared__ double sred[MTPB];
  int tid = threadIdx.x;
  int blk = blockIdx.x;
  int itile = blk >> 3;
  int ch = blk & 7;
  int j0 = ch * MCHK;
  for (int u = tid; u < MCHK; u += MTPB) {
    sM[u] = M4[j0 + u];
    sY[u] = Y4[j0 + u];
  }
  __syncthreads();
  int i = itile * MTPB + tid;
  float4 mi = M4[i];
  float4 yi = Y4[i];
  double szz = 0.0, szy = 0.0, syy = 0.0;
  for (int jj = 0; jj < MCHK; ++jj) {
    float4 mj = sM[jj];
    float4 yj = sY[jj];
    float d0 = mi.x - mj.x, d1 = mi.y - mj.y;
    float a = fmaf(d1, d1, d0 * d0);
    float u0 = mi.z - mj.z, u1 = mi.w - mj.w;
    float v0 = mi.z - yj.z, v1 = mi.w - yj.w;
    float w0 = yi.z - yj.z, w1 = yi.w - yj.w;
    float dzz = fmaf(u0, u0, fmaf(u1, u1, a));
    float dzy = fmaf(v0, v0, fmaf(v1, v1, a));
    float dyy = fmaf(w0, w0, fmaf(w1, w1, a));
    szz += (double)__expf(-0.5f * dzz);
    szy += (double)__expf(-0.5f * dzy);
    syy += (double)__expf(-0.5f * dyy);
  }
  double v[3] = {szz, szy, syy};
  for (int k = 0; k < 3; ++k) {
    sred[tid] = v[k];
    __syncthreads();
    for (int st = MTPB >> 1; st >= 1; st >>= 1) {
      if (tid < st) sred[tid] += sred[tid + st];
      __syncthreads();
    }
    if (tid == 0) mmdpart[blk * 3 + k] = sred[0];
    __syncthreads();
  }
}

__device__ __forceinline__ float evalK(float4 u, float nu, float4 ws, float nss) {
  float tt = fmaf(u.x, ws.x, fmaf(u.y, ws.y, fmaf(u.z, ws.z, u.w * ws.w)));
  return EXP2F(tt - nu - nss);
}

// ---------------- G = delta I + eta W + C^T C (f64) ----------------
extern "C" __global__ void __launch_bounds__(256)
k_gbuild(const float4* __restrict__ U4, const float4* __restrict__ W4,
         const float* __restrict__ NS, double* __restrict__ G)
{
  __shared__ float ea[8][32];
  __shared__ float eb[8][32];
  int tid = threadIdx.x;
  int blk = blockIdx.x;
  int a0 = (blk >> 4) * 32;
  int b0 = (blk & 15) * 32;
  int arow = tid >> 5;           // 0..7
  int bl = tid & 31;             // 0..31
  int sa = (a0 + bl) * SSTR;
  int sb = (b0 + bl) * SSTR;
  float4 wsa = W4[sa]; float nsa = NS[sa];
  float4 wsb = W4[sb]; float nsb = NS[sb];
  double acc[4] = {0.0, 0.0, 0.0, 0.0};
  for (int ic = 0; ic < NPTS / 8; ++ic) {
    int i = ic * 8 + arow;
    float4 u = U4[i];
    float nu = NS[i];
    ea[arow][bl] = evalK(u, nu, wsa, nsa);
    eb[arow][bl] = evalK(u, nu, wsb, nsb);
    __syncthreads();
#pragma unroll
    for (int kk = 0; kk < 4; ++kk) {
      int al = (tid >> 5) + 8 * kk;
      double s = 0.0;
#pragma unroll
      for (int ii = 0; ii < 8; ++ii)
        s += (double)ea[ii][al] * (double)eb[ii][bl];
      acc[kk] += s;
    }
    __syncthreads();
  }
#pragma unroll
  for (int kk = 0; kk < 4; ++kk) {
    int al = (tid >> 5) + 8 * kk;
    int a = a0 + al, b = b0 + bl;
    int ia = a * SSTR;
    float4 ua = U4[ia];
    float na = NS[ia];
    double w_ab = (double)evalK(ua, na, wsb, nsb);   // K(S_a, S_b)
    double g = acc[kk] + NUG * w_ab + ((a == b) ? DELTA : 0.0);
    G[(size_t)a * MNY + b] = g;
  }
}

// ---------------- block Gauss-Jordan: 16 pivots per launch (ping-pong, f64) ----
// 64 blocks x 512 threads; block owns 8 rows; every block redundantly inverts
// the 16x16 panel in LDS and computes W = Pinv*R (64 KB LDS); elimination
// order matches the scalar pivot sequence. (Verified correct in R18's pass.)
extern "C" __global__ void __launch_bounds__(512)
k_gjpanel(const double* __restrict__ Mc, double* __restrict__ Mn, int k0)
{
  __shared__ double pm[16][16];
  __shared__ double sW[16][MNY];            // 64 KB
  __shared__ double cl[8][16];
  __shared__ double trow[16], tcol[16];
  __shared__ double ps;
  int tid = threadIdx.x;
  int blk = blockIdx.x;

  if (tid < 256)
    pm[tid >> 4][tid & 15] = Mc[(size_t)(k0 + (tid >> 4)) * MNY + k0 + (tid & 15)];
  __syncthreads();
  for (int piv = 0; piv < 16; ++piv) {
    if (tid == 0) ps = 1.0 / pm[piv][piv];
    if (tid < 16) { trow[tid] = pm[piv][tid]; tcol[tid] = pm[tid][piv]; }
    __syncthreads();
    double p = ps;
    if (tid < 256) {
      int r = tid >> 4, c = tid & 15;
      double v;
      if (r == piv && c == piv) v = p;
      else if (r == piv)        v = trow[c] * p;
      else if (c == piv)        v = -tcol[r] * p;
      else                      v = fma(-tcol[r] * p, trow[c], pm[r][c]);
      pm[r][c] = v;
    }
    __syncthreads();
  }
  {
    double m[16];
#pragma unroll
    for (int s = 0; s < 16; ++s) m[s] = Mc[(size_t)(k0 + s) * MNY + tid];
#pragma unroll
    for (int r = 0; r < 16; ++r) {
      double acc = 0.0;
#pragma unroll
      for (int s = 0; s < 16; ++s) acc = fma(pm[r][s], m[s], acc);
      sW[r][tid] = acc;
    }
  }
  if (tid < 128)
    cl[tid >> 4][tid & 15] = Mc[(size_t)(blk * 8 + (tid >> 4)) * MNY + k0 + (tid & 15)];
  __syncthreads();

  int jk = tid - k0;
  bool inK = (jk >= 0 && jk < 16);
#pragma unroll
  for (int rr = 0; rr < 8; ++rr) {
    int i = blk * 8 + rr;
    int pr = i - k0;
    double v;
    if (pr >= 0 && pr < 16) {                // panel-owner row
      v = inK ? pm[pr][jk] : sW[pr][tid];
    } else if (inK) {
      double acc = 0.0;
#pragma unroll
      for (int s = 0; s < 16; ++s) acc = fma(cl[rr][s], pm[s][jk], acc);
      v = -acc;
    } else {
      double acc = Mc[(size_t)i * MNY + tid];
#pragma unroll
      for (int s = 0; s < 16; ++s) acc = fma(-cl[rr][s], sW[s][tid], acc);
      v = acc;
    }
    Mn[(size_t)i * MNY + tid] = v;
  }
}

// ---------------- D = C * Ginv (f32 out, f64 accum); 512 blocks x 512 thr ----
extern "C" __global__ void __launch_bounds__(512)
k_dbuild(const float4* __restrict__ U4, const float4* __restrict__ W4,
         const float* __restrict__ NS, const double* __restrict__ Ginv,
         float* __restrict__ D)
{
  __shared__ float sc[16][MNY];              // 32 KB
  __shared__ float4 su[16];
  __shared__ float snl[16];
  int tid = threadIdx.x;
  int blk = blockIdx.x;
  int i0 = blk * 16;
  if (tid < 16) { su[tid] = U4[i0 + tid]; snl[tid] = NS[i0 + tid]; }
  __syncthreads();
  {
    int si = tid * SSTR;
    float4 ws = W4[si];
    float nss = NS[si];
#pragma unroll
    for (int r = 0; r < 16; ++r)
      sc[r][tid] = evalK(su[r], snl[r], ws, nss);
  }
  __syncthreads();
  double acc[16];
#pragma unroll
  for (int r = 0; r < 16; ++r) acc[r] = 0.0;
  for (int k = 0; k < MNY; ++k) {
    double g = Ginv[(size_t)k * MNY + tid];  // coalesced
#pragma unroll
    for (int r = 0; r < 16; ++r)
      acc[r] = fma((double)sc[r][k], g, acc[r]);   // LDS broadcast
  }
#pragma unroll
  for (int r = 0; r < 16; ++r)
    D[(size_t)(i0 + r) * MNY + tid] = (float)acc[r];
}

// ---------------- K1: big matvec q = K p (+eta p), p = z + beta p ----------------
extern "C" __global__ void __launch_bounds__(512, 4)
k_matvec(const float4* __restrict__ U4, const float4* __restrict__ W4,
         const float* __restrict__ NS,
         const float2* __restrict__ Zv, const float2* __restrict__ Pfp,
         float2* __restrict__ Pfc, float2* __restrict__ qpart,
         double* __restrict__ pqpart, const double* __restrict__ rhopart, int t)
{
  __shared__ float4 sw[JCH];
  __shared__ float4 sa[JCH];
  __shared__ double s1[512], s2[512];
  __shared__ double sc[2];
  int tid = threadIdx.x;
  int blk = blockIdx.x;
  int it = blk >> 4;
  int ch = blk & (NCH - 1);
  int j = ch * JCH + tid;

  float4 wj = W4[j];
  float nj = NS[j];
  float2 zj = Zv[j];
  float2 pj = Pfp[j];

  // beta = rho_{t-1} / rho_{t-2}
  if (t == 1) {
    if (tid < 2) sc[tid] = 0.0;
    __syncthreads();
  } else {
    const double* cur = rhopart + ((t - 1) & 1) * 128;
    const double* prv = rhopart + ((t - 2) & 1) * 128;
    if (tid < 128) { s1[tid] = cur[tid]; s2[tid] = prv[tid]; }
    __syncthreads();
    for (int st = 64; st >= 2; st >>= 1) {
      if (tid < st) { s1[tid] += s1[tid + st]; s2[tid] += s2[tid + st]; }
      __syncthreads();
    }
    if (tid < 2) sc[tid] = s1[tid] / s2[tid];
    __syncthreads();
  }
  float b0 = (float)sc[0], b1 = (float)sc[1];

  sw[tid] = wj;
  sa[tid] = make_float4(nj, fmaf(b0, pj.x, zj.x), fmaf(b1, pj.y, zj.y), 0.f);
  __syncthreads();

  int js = tid & (NJS - 1);
  int ig = tid >> 4;
  int i0 = it * ITILE + ig * IB;
  float4 ui[IB];
  float ni[IB];
#pragma unroll
  for (int k = 0; k < IB; ++k) { ui[k] = U4[i0 + k]; ni[k] = NS[i0 + k]; }
  float qa0[IB], qa1[IB];
#pragma unroll
  for (int k = 0; k < IB; ++k) { qa0[k] = 0.f; qa1[k] = 0.f; }
#pragma unroll 4
  for (int jj = 0; jj < JPT; ++jj) {
    int jl = jj * NJS + js;
    float4 w = sw[jl];
    float4 aa = sa[jl];
#pragma unroll
    for (int k = 0; k < IB; ++k) {
      float ttn = -(ni[k] + aa.x);
      ttn = fmaf(ui[k].x, w.x, ttn);
      ttn = fmaf(ui[k].y, w.y, ttn);
      ttn = fmaf(ui[k].z, w.z, ttn);
      ttn = fmaf(ui[k].w, w.w, ttn);
      float e = EXP2F(ttn);
      qa0[k] = fmaf(e, aa.y, qa0[k]);
      qa1[k] = fmaf(e, aa.z, qa1[k]);
    }
  }
#pragma unroll
  for (int k = 0; k < IB; ++k) {
#pragma unroll
    for (int d = 8; d >= 1; d >>= 1) {
      qa0[k] += __shfl_down(qa0[k], (unsigned)d, 16);
      qa1[k] += __shfl_down(qa1[k], (unsigned)d, 16);
    }
  }
  double pq0 = 0.0, pq1 = 0.0;
  if (js == 0) {
    int owner = (it & (NCH - 1));
#pragma unroll
    for (int k = 0; k < IB; ++k) {
      int i = i0 + k;
      float2 zi = Zv[i];
      float2 pi = Pfp[i];
      float pn0 = fmaf(b0, pi.x, zi.x);
      float pn1 = fmaf(b1, pi.y, zi.y);
      qpart[(size_t)ch * NPTS + i] = make_float2(qa0[k], qa1[k]);
      if (ch == owner) Pfc[i] = make_float2(pn0, pn1);
      pq0 += (double)pn0 * (double)qa0[k];
      pq1 += (double)pn1 * (double)qa1[k];
      if (ch == 0) {
        pq0 += NUG * (double)pn0 * (double)pn0;
        pq1 += NUG * (double)pn1 * (double)pn1;
      }
    }
  }
  s1[tid] = pq0;
  s2[tid] = pq1;
  __syncthreads();
  for (int st = 256; st >= 1; st >>= 1) {
    if (tid < st) { s1[tid] += s1[tid + st]; s2[tid] += s2[tid + st]; }
    __syncthreads();
  }
  if (tid == 0) { pqpart[blk * 2 + 0] = s1[0]; pqpart[blk * 2 + 1] = s2[0]; }
}

// ---------------- K2: alpha, x/r update, y1 = C^T r partials ----------------
extern "C" __global__ void __launch_bounds__(256)
k_update(const float* __restrict__ qpartf, const float2* __restrict__ Pfc,
         double* __restrict__ r64, double* __restrict__ x64,
         const float4* __restrict__ U4, const float4* __restrict__ W4,
         const float* __restrict__ NS,
         const double* __restrict__ pqpart, const double* __restrict__ rhopart,
         double* __restrict__ y1part, int t)
{
  __shared__ double s1[256];
  __shared__ double s2[128];
  __shared__ double alpha2[2];
  __shared__ float4 su[128];
  __shared__ float snl[128];
  __shared__ double rl[2][128];
  int tid = threadIdx.x;
  int blk = blockIdx.x;
  int idx = blk * 256 + tid;
  double rv;
  if (t > 0) {
    s1[tid] = pqpart[tid] + pqpart[tid + 256] + pqpart[tid + 512] + pqpart[tid + 768];
    if (tid < 128) s2[tid] = rhopart[((t - 1) & 1) * 128 + tid];
    __syncthreads();
    for (int st = 128; st >= 2; st >>= 1) {
      if (tid < st) s1[tid] += s1[tid + st];
      if (st <= 64 && tid < st) s2[tid] += s2[tid + st];
      __syncthreads();
    }
    if (tid < 2) alpha2[tid] = s2[tid] / s1[tid];
    __syncthreads();
    double a = alpha2[idx & 1];
    float pn = ((const float*)Pfc)[idx];
    double q = 0.0;
#pragma unroll
    for (int c = 0; c < NCH; ++c) q += (double)qpartf[(size_t)c * N2 + idx];
    q = fma((double)NUG, (double)pn, q);
    rv = fma(-a, q, r64[idx]);
    x64[idx] = fma(a, (double)pn, x64[idx]);
    r64[idx] = rv;
  } else {
    rv = r64[idx];
  }
  rl[idx & 1][tid >> 1] = rv;
  if (tid < 128) {
    su[tid] = U4[blk * 128 + tid];
    snl[tid] = NS[blk * 128 + tid];
  }
  __syncthreads();
  for (int rr = 0; rr < MNY / 256; ++rr) {
    int s = rr * 256 + tid;
    int si = s * SSTR;
    float4 ws = W4[si];
    float nss = NS[si];
    double y0 = 0.0, y1v = 0.0;
#pragma unroll 4
    for (int il = 0; il < 128; ++il) {
      float4 u = su[il];
      float tt = fmaf(u.x, ws.x, fmaf(u.y, ws.y, fmaf(u.z, ws.z, u.w * ws.w)));
      float e = EXP2F(tt - snl[il] - nss);
      y0 = fma((double)e, rl[0][il], y0);
      y1v = fma((double)e, rl[1][il], y1v);
    }
    y1part[(size_t)s * 128 + blk * 2 + 0] = y0;
    y1part[(size_t)s * 128 + blk * 2 + 1] = y1v;
  }
}

// ---------------- K3 (D path): z = (r - D y1)/eta ; rho partials ----------------
extern "C" __global__ void __launch_bounds__(256)
k_dz(const double* __restrict__ r64, const double* __restrict__ y1part,
     const float* __restrict__ D, float2* __restrict__ Zv,
     double* __restrict__ rhopart, int t)
{
  __shared__ double ly1[MNY][2];
  __shared__ double zl[128][2];
  __shared__ double s1[256], s2[256];
  int tid = threadIdx.x;
  int blk = blockIdx.x;
  for (int s = tid; s < MNY; s += 256) {
    const double* base = y1part + (size_t)s * 128;
    double a0 = 0.0, a1 = 0.0;
#pragma unroll 8
    for (int b = 0; b < 64; ++b) { a0 += base[2 * b]; a1 += base[2 * b + 1]; }
    ly1[s][0] = a0; ly1[s][1] = a1;
  }
  __syncthreads();
  {
    int lane = tid & 63, wv = tid >> 6;      // 4 waves
    for (int rnd = 0; rnd < 32; ++rnd) {
      int pt = wv * 32 + rnd;
      const float* drow = D + (size_t)(blk * 128 + pt) * MNY;
      double a0 = 0.0, a1 = 0.0;
#pragma unroll
      for (int m = 0; m < MNY / 64; ++m) {
        int s = lane + 64 * m;               // coalesced across lanes
        double dv = (double)drow[s];
        a0 = fma(dv, ly1[s][0], a0);
        a1 = fma(dv, ly1[s][1], a1);
      }
#pragma unroll
      for (int d = 32; d >= 1; d >>= 1) {
        a0 += __shfl_down(a0, (unsigned)d, 64);
        a1 += __shfl_down(a1, (unsigned)d, 64);
      }
      if (lane == 0) { zl[pt][0] = a0; zl[pt][1] = a1; }
    }
  }
  __syncthreads();
  double rz0 = 0.0, rz1 = 0.0;
  if (tid < 128) {
    int i = blk * 128 + tid;
    double r0 = r64[2 * i], r1 = r64[2 * i + 1];
    double z0 = (r0 - zl[tid][0]) * INVNUG;
    double z1 = (r1 - zl[tid][1]) * INVNUG;
    Zv[i] = make_float2((float)z0, (float)z1);
    rz0 = r0 * z0;
    rz1 = r1 * z1;
  }
  s1[tid] = rz0;
  s2[tid] = rz1;
  __syncthreads();
  for (int st = 128; st >= 1; st >>= 1) {
    if (tid < st) { s1[tid] += s1[tid + st]; s2[tid] += s2[tid + st]; }
    __syncthreads();
  }
  if (tid == 0) {
    rhopart[(t & 1) * 128 + blk * 2 + 0] = s1[0];
    rhopart[(t & 1) * 128 + blk * 2 + 1] = s2[0];
  }
}

// ---------------- K34 fallback (no-D path) ----------------
extern "C" __global__ void __launch_bounds__(256)
k_y2z(const float4* __restrict__ U4, const float4* __restrict__ W4,
      const float* __restrict__ NS, const double* __restrict__ r64,
      const double* __restrict__ y1part, const double* __restrict__ Ginv,
      float2* __restrict__ Zv, double* __restrict__ rhopart, int t)
{
  __shared__ double ly1[MNY][2];
  __shared__ double ly2[MNY][2];
  __shared__ double s1[256], s2[256];
  int tid = threadIdx.x;
  int blk = blockIdx.x;
  for (int s = tid; s < MNY; s += 256) {
    const double* base = y1part + (size_t)s * 128;
    double a0 = 0.0, a1 = 0.0;
#pragma unroll 8
    for (int b = 0; b < 64; ++b) { a0 += base[2 * b]; a1 += base[2 * b + 1]; }
    ly1[s][0] = a0; ly1[s][1] = a1;
  }
  __syncthreads();
  {
    int g = tid >> 5, l = tid & 31;
    for (int ss = 0; ss < MNY / 8; ++ss) {
      int so = g * (MNY / 8) + ss;
      const double* grow = Ginv + (size_t)so * MNY;
      double c0 = 0.0, c1 = 0.0;
#pragma unroll
      for (int m = 0; m < MNY / 32; ++m) {
        int jj = m * 32 + l;
        double gv = grow[jj];
        c0 = fma(gv, ly1[jj][0], c0);
        c1 = fma(gv, ly1[jj][1], c1);
      }
#pragma unroll
      for (int d = 16; d >= 1; d >>= 1) {
        c0 += __shfl_down(c0, (unsigned)d, 32);
        c1 += __shfl_down(c1, (unsigned)d, 32);
      }
      if (l == 0) { ly2[so][0] = c0; ly2[so][1] = c1; }
    }
  }
  __syncthreads();
  int pt = tid & 127;
  int half = tid >> 7;
  int i = blk * 128 + pt;
  float4 u = U4[i];
  float nu = NS[i];
  double acc0 = 0.0, acc1 = 0.0;
  int sbase = half * (MNY / 2);
#pragma unroll 4
  for (int s = 0; s < MNY / 2; ++s) {
    int so = sbase + s;
    int si = so * SSTR;
    float4 ws = W4[si];
    float nss = NS[si];
    float tt = fmaf(u.x, ws.x, fmaf(u.y, ws.y, fmaf(u.z, ws.z, u.w * ws.w)));
    float e = EXP2F(tt - nu - nss);
    acc0 = fma((double)e, ly2[so][0], acc0);
    acc1 = fma((double)e, ly2[so][1], acc1);
  }
  s1[tid] = acc0;
  s2[tid] = acc1;
  __syncthreads();
  double rz0 = 0.0, rz1 = 0.0;
  if (tid < 128) {
    double a0 = s1[tid] + s1[tid + 128];
    double a1 = s2[tid] + s2[tid + 128];
    double r0 = r64[2 * i], r1 = r64[2 * i + 1];
    double z0 = (r0 - a0) * INVNUG;
    double z1 = (r1 - a1) * INVNUG;
    Zv[i] = make_float2((float)z0, (float)z1);
    rz0 = r0 * z0;
    rz1 = r1 * z1;
  }
  __syncthreads();
  s1[tid] = rz0;
  s2[tid] = rz1;
  __syncthreads();
  for (int st = 128; st >= 1; st >>= 1) {
    if (tid < st) { s1[tid] += s1[tid + st]; s2[tid] += s2[tid + st]; }
    __syncthreads();
  }
  if (tid == 0) {
    rhopart[(t & 1) * 128 + blk * 2 + 0] = s1[0];
    rhopart[(t & 1) * 128 + blk * 2 + 1] = s2[0];
  }
}

// ---------------- final combine ----------------
extern "C" __global__ void __launch_bounds__(256)
k_final(const float* __restrict__ Z, const double* __restrict__ x64,
        const double* __restrict__ mmdpart, float* __restrict__ out)
{
  __shared__ double sred[256];
  int tid = threadIdx.x;
  double zx = 0.0;
  for (int idx = tid; idx < N2; idx += 256)
    zx += (double)Z[idx] * x64[idx];
  double acc[4];
  acc[0] = zx;
  acc[1] = mmdpart[tid * 3 + 0];
  acc[2] = mmdpart[tid * 3 + 1];
  acc[3] = mmdpart[tid * 3 + 2];
  double tot[4];
  for (int k = 0; k < 4; ++k) {
    sred[tid] = acc[k];
    __syncthreads();
    for (int st = 128; st >= 1; st >>= 1) {
      if (tid < st) sred[tid] += sred[tid + st];
      __syncthreads();
    }
    tot[k] = sred[0];
    __syncthreads();
  }
  if (tid == 0) {
    double nn = (double)NPTS * (double)NPTS;
    double mmd = (tot[1] - 2.0 * tot[2] + tot[3]) / nn;
    out[0] = (float)(mmd + LAM * tot[0]);
  }
}

extern "C" void kernel_launch(void* const* d_in, const int* in_sizes, int n_in,
                              void* d_out, int out_size, void* d_ws, size_t ws_size,
                              hipStream_t stream)
{
  (void)in_sizes; (void)n_in; (void)out_size;
  const float* Xmu  = (const float*)d_in[0];
  const float* Yeta = (const float*)d_in[1];
  const float* Ymu  = (const float*)d_in[2];
  const float* Z    = (const float*)d_in[3];
  float* out = (float*)d_out;

  char* w = (char*)d_ws;
  float4* U4      = (float4*)(w);                      // 128K
  float4* W4      = (float4*)(w + (128 << 10));        // 128K
  float*  NS      = (float*)(w + (256 << 10));         // 32K
  float4* M4      = (float4*)(w + (288 << 10));        // 128K
  float4* Y4      = (float4*)(w + (416 << 10));        // 128K
  float2* Zv      = (float2*)(w + (544 << 10));        // 64K
  float2* Pf[2]   = { (float2*)(w + (608 << 10)), (float2*)(w + (672 << 10)) };
  double* r64     = (double*)(w + (736 << 10));        // 128K
  double* x64     = (double*)(w + (864 << 10));        // 128K
  float2* qpart   = (float2*)(w + (992 << 10));        // 1M
  double* pqpart  = (double*)(w + (2016 << 10));       // 8K
  double* rhopart = (double*)(w + (2024 << 10));       // 2K
  double* y1part  = (double*)(w + (2026 << 10));       // 512K
  double* mmdpart = (double*)(w + (2546 << 10));       // 6K
  double* Gb0     = (double*)(w + (2552 << 10));       // 2M
  double* Gb1     = (double*)(w + (4600 << 10));       // 2M
  float*  D       = (float*)(w + (6656 << 10));        // 16M
  int useD = (ws_size >= ((size_t)(6656 + 16384) << 10)) ? 1 : 0;

  hipLaunchKernelGGL(k_setup, dim3(64), dim3(256), 0, stream,
                     Xmu, Yeta, Ymu, Z, U4, W4, NS, M4, Y4,
                     Pf[0], Pf[1], r64, x64);
  hipLaunchKernelGGL(k_mmd, dim3(256), dim3(MTPB), 0, stream, M4, Y4, mmdpart);
  hipLaunchKernelGGL(k_gbuild, dim3(256), dim3(256), 0, stream, U4, W4, NS, Gb0);
  for (int p = 0; p < MNY / 16; ++p) {       // 32 panel launches
    double* Mc = (p & 1) ? Gb1 : Gb0;
    double* Mn = (p & 1) ? Gb0 : Gb1;
    hipLaunchKernelGGL(k_gjpanel, dim3(64), dim3(512), 0, stream, Mc, Mn, p * 16);
  }
  double* Ginv = Gb0;                    // 32 panels: last write lands in Gb0
  if (useD)
    hipLaunchKernelGGL(k_dbuild, dim3(512), dim3(512), 0, stream,
                       U4, W4, NS, Ginv, D);

  // bootstrap: y1 = C^T r0; z0 = P r0; rho_0
  hipLaunchKernelGGL(k_update, dim3(64), dim3(256), 0, stream,
                     (const float*)qpart, Pf[0], r64, x64, U4, W4, NS,
                     pqpart, rhopart, y1part, 0);
  if (useD)
    hipLaunchKernelGGL(k_dz, dim3(64), dim3(256), 0, stream,
                       r64, y1part, D, Zv, rhopart, 0);
  else
    hipLaunchKernelGGL(k_y2z, dim3(64), dim3(256), 0, stream,
                       U4, W4, NS, r64, y1part, Ginv, Zv, rhopart, 0);

  for (int t = 1; t <= T_ITERS; ++t) {
    float2* Pprev = Pf[(t - 1) & 1];
    float2* Pcur  = Pf[t & 1];
    hipLaunchKernelGGL(k_matvec, dim3(NBLK1), dim3(512), 0, stream,
                       U4, W4, NS, Zv, Pprev, Pcur, qpart, pqpart, rhopart, t);
    hipLaunchKernelGGL(k_update, dim3(64), dim3(256), 0, stream,
                       (const float*)qpart, Pcur, r64, x64, U4, W4, NS,
                       pqpart, rhopart, y1part, t);
    if (t < T_ITERS) {
      if (useD)
        hipLaunchKernelGGL(k_dz, dim3(64), dim3(256), 0, stream,
                           r64, y1part, D, Zv, rhopart, t);
      else
        hipLaunchKernelGGL(k_y2z, dim3(64), dim3(256), 0, stream,
                           U4, W4, NS, r64, y1part, Ginv, Zv, rhopart, t);
    }
  }
  hipLaunchKernelGGL(k_final, dim3(1), dim3(256), 0, stream,
                     Z, x64, mmdpart, out);
}

// Round 20
// 9432.732 us; speedup vs baseline: 1.6028x; 1.1142x over previous
//
#include <hip/hip_runtime.h>

#define NPTS 8192
#define N2 (NPTS * 2)
#define NCH 16             // j-chunks for big matvec
#define JCH (NPTS / NCH)   // 512
#define ITILE 256          // i-rows per matvec block
#define NIT (NPTS / ITILE) // 32
#define NBLK1 (NIT * NCH)  // 512 matvec blocks
#define IB 8
#define NJS 16             // j-slices in matvec
#define JPT (JCH / NJS)    // 32
#define MNY 512            // Nystrom rank
#define SSTR 16            // landmark stride
#define T_ITERS 120
#define NUG 1.0e-4
#define INVNUG 1.0e4
#define DELTA 1.0e-2
#define LAM 1.0e-5

#if __has_builtin(__builtin_amdgcn_exp2f)
#define EXP2F(x) __builtin_amdgcn_exp2f(x)
#else
#define EXP2F(x) __expf(0.6931471805599453f * (x))
#endif

// ---------------- setup: scaled coords, f64 CG state ----------------
extern "C" __global__ void __launch_bounds__(256)
k_setup(const float* __restrict__ Xmu, const float* __restrict__ Yeta,
        const float* __restrict__ Ymu, const float* __restrict__ Z,
        float4* __restrict__ U4, float4* __restrict__ W4, float* __restrict__ NS,
        float4* __restrict__ M4, float4* __restrict__ Y4,
        float2* __restrict__ Pf0, float2* __restrict__ Pf1,
        double* __restrict__ r64, double* __restrict__ x64)
{
  const float c2 = 0.84932180028802f;        // 1/sqrt(2 ln 2)
  int tid = threadIdx.x;
  int idx = blockIdx.x * 256 + tid;          // 64 blocks -> 16384
  int i = idx >> 1;
  r64[idx] = (double)Z[idx];
  x64[idx] = 0.0;
  if ((idx & 1) == 0) {
    float a0 = Xmu[2 * i], a1 = Xmu[2 * i + 1];
    float e0 = Yeta[2 * i], e1 = Yeta[2 * i + 1];
    float m0 = Ymu[2 * i], m1 = Ymu[2 * i + 1];
    float z0 = Z[2 * i], z1 = Z[2 * i + 1];
    float u0 = c2 * a0, u1 = c2 * a1, u2 = c2 * e0, u3 = c2 * e1;
    float n = fmaf(u3, u3, fmaf(u2, u2, fmaf(u1, u1, u0 * u0)));
    U4[i] = make_float4(u0, u1, u2, u3);
    W4[i] = make_float4(2.f * u0, 2.f * u1, 2.f * u2, 2.f * u3);
    NS[i] = n;
    M4[i] = make_float4(a0, a1, e0 + z0, e1 + z1);
    Y4[i] = make_float4(a0, a1, m0, m1);
    Pf0[i] = make_float2(0.f, 0.f);
    Pf1[i] = make_float2(0.f, 0.f);
  }
}

// ---------------- MMD: three fused Gram sums ----------------
#define MTPB 256
#define MCHK 1024
extern "C" __global__ void __launch_bounds__(MTPB)
k_mmd(const float4* __restrict__ M4, const float4* __restrict__ Y4,
      double* __restrict__ mmdpart)
{
  __shared__ float4 sM[MCHK];
  __shared__ float4 sY[MCHK];
  __shared__ double sred[MTPB];
  int tid = threadIdx.x;
  int blk = blockIdx.x;
  int itile = blk >> 3;
  int ch = blk & 7;
  int j0 = ch * MCHK;
  for (int u = tid; u < MCHK; u += MTPB) {
    sM[u] = M4[j0 + u];
    sY[u] = Y4[j0 + u];
  }
  __syncthreads();
  int i = itile * MTPB + tid;
  float4 mi = M4[i];
  float4 yi = Y4[i];
  double szz = 0.0, szy = 0.0, syy = 0.0;
  for (int jj = 0; jj < MCHK; ++jj) {
    float4 mj = sM[jj];
    float4 yj = sY[jj];
    float d0 = mi.x - mj.x, d1 = mi.y - mj.y;
    float a = fmaf(d1, d1, d0 * d0);
    float u0 = mi.z - mj.z, u1 = mi.w - mj.w;
    float v0 = mi.z - yj.z, v1 = mi.w - yj.w;
    float w0 = yi.z - yj.z, w1 = yi.w - yj.w;
    float dzz = fmaf(u0, u0, fmaf(u1, u1, a));
    float dzy = fmaf(v0, v0, fmaf(v1, v1, a));
    float dyy = fmaf(w0, w0, fmaf(w1, w1, a));
    szz += (double)__expf(-0.5f * dzz);
    szy += (double)__expf(-0.5f * dzy);
    syy += (double)__expf(-0.5f * dyy);
  }
  double v[3] = {szz, szy, syy};
  for (int k = 0; k < 3; ++k) {
    sred[tid] = v[k];
    __syncthreads();
    for (int st = MTPB >> 1; st >= 1; st >>= 1) {
      if (tid < st) sred[tid] += sred[tid + st];
      __syncthreads();
    }
    if (tid == 0) mmdpart[blk * 3 + k] = sred[0];
    __syncthreads();
  }
}

__device__ __forceinline__ float evalK(float4 u, float nu, float4 ws, float nss) {
  float tt = fmaf(u.x, ws.x, fmaf(u.y, ws.y, fmaf(u.z, ws.z, u.w * ws.w)));
  return EXP2F(tt - nu - nss);
}

// ---------------- G = delta I + eta W + C^T C (f64) ----------------
extern "C" __global__ void __launch_bounds__(256)
k_gbuild(const float4* __restrict__ U4, const float4* __restrict__ W4,
         const float* __restrict__ NS, double* __restrict__ G)
{
  __shared__ float ea[8][32];
  __shared__ float eb[8][32];
  int tid = threadIdx.x;
  int blk = blockIdx.x;
  int a0 = (blk >> 4) * 32;
  int b0 = (blk & 15) * 32;
  int arow = tid >> 5;           // 0..7
  int bl = tid & 31;             // 0..31
  int sa = (a0 + bl) * SSTR;
  int sb = (b0 + bl) * SSTR;
  float4 wsa = W4[sa]; float nsa = NS[sa];
  float4 wsb = W4[sb]; float nsb = NS[sb];
  double acc[4] = {0.0, 0.0, 0.0, 0.0};
  for (int ic = 0; ic < NPTS / 8; ++ic) {
    int i = ic * 8 + arow;
    float4 u = U4[i];
    float nu = NS[i];
    ea[arow][bl] = evalK(u, nu, wsa, nsa);
    eb[arow][bl] = evalK(u, nu, wsb, nsb);
    __syncthreads();
#pragma unroll
    for (int kk = 0; kk < 4; ++kk) {
      int al = (tid >> 5) + 8 * kk;
      double s = 0.0;
#pragma unroll
      for (int ii = 0; ii < 8; ++ii)
        s += (double)ea[ii][al] * (double)eb[ii][bl];
      acc[kk] += s;
    }
    __syncthreads();
  }
#pragma unroll
  for (int kk = 0; kk < 4; ++kk) {
    int al = (tid >> 5) + 8 * kk;
    int a = a0 + al, b = b0 + bl;
    int ia = a * SSTR;
    float4 ua = U4[ia];
    float na = NS[ia];
    double w_ab = (double)evalK(ua, na, wsb, nsb);   // K(S_a, S_b)
    double g = acc[kk] + NUG * w_ab + ((a == b) ? DELTA : 0.0);
    G[(size_t)a * MNY + b] = g;
  }
}

// ---------------- block Gauss-Jordan: 16 pivots per launch (ping-pong, f64) ----
extern "C" __global__ void __launch_bounds__(512)
k_gjpanel(const double* __restrict__ Mc, double* __restrict__ Mn, int k0)
{
  __shared__ double pm[16][16];
  __shared__ double sW[16][MNY];            // 64 KB
  __shared__ double cl[8][16];
  __shared__ double trow[16], tcol[16];
  __shared__ double ps;
  int tid = threadIdx.x;
  int blk = blockIdx.x;

  if (tid < 256)
    pm[tid >> 4][tid & 15] = Mc[(size_t)(k0 + (tid >> 4)) * MNY + k0 + (tid & 15)];
  __syncthreads();
  for (int piv = 0; piv < 16; ++piv) {
    if (tid == 0) ps = 1.0 / pm[piv][piv];
    if (tid < 16) { trow[tid] = pm[piv][tid]; tcol[tid] = pm[tid][piv]; }
    __syncthreads();
    double p = ps;
    if (tid < 256) {
      int r = tid >> 4, c = tid & 15;
      double v;
      if (r == piv && c == piv) v = p;
      else if (r == piv)        v = trow[c] * p;
      else if (c == piv)        v = -tcol[r] * p;
      else                      v = fma(-tcol[r] * p, trow[c], pm[r][c]);
      pm[r][c] = v;
    }
    __syncthreads();
  }
  {
    double m[16];
#pragma unroll
    for (int s = 0; s < 16; ++s) m[s] = Mc[(size_t)(k0 + s) * MNY + tid];
#pragma unroll
    for (int r = 0; r < 16; ++r) {
      double acc = 0.0;
#pragma unroll
      for (int s = 0; s < 16; ++s) acc = fma(pm[r][s], m[s], acc);
      sW[r][tid] = acc;
    }
  }
  if (tid < 128)
    cl[tid >> 4][tid & 15] = Mc[(size_t)(blk * 8 + (tid >> 4)) * MNY + k0 + (tid & 15)];
  __syncthreads();

  int jk = tid - k0;
  bool inK = (jk >= 0 && jk < 16);
#pragma unroll
  for (int rr = 0; rr < 8; ++rr) {
    int i = blk * 8 + rr;
    int pr = i - k0;
    double v;
    if (pr >= 0 && pr < 16) {                // panel-owner row
      v = inK ? pm[pr][jk] : sW[pr][tid];
    } else if (inK) {
      double acc = 0.0;
#pragma unroll
      for (int s = 0; s < 16; ++s) acc = fma(cl[rr][s], pm[s][jk], acc);
      v = -acc;
    } else {
      double acc = Mc[(size_t)i * MNY + tid];
#pragma unroll
      for (int s = 0; s < 16; ++s) acc = fma(-cl[rr][s], sW[s][tid], acc);
      v = acc;
    }
    Mn[(size_t)i * MNY + tid] = v;
  }
}

// ---------------- D = C * Ginv (f32 out, f64 accum); 512 blocks x 512 thr ----
extern "C" __global__ void __launch_bounds__(512)
k_dbuild(const float4* __restrict__ U4, const float4* __restrict__ W4,
         const float* __restrict__ NS, const double* __restrict__ Ginv,
         float* __restrict__ D)
{
  __shared__ float sc[16][MNY];              // 32 KB
  __shared__ float4 su[16];
  __shared__ float snl[16];
  int tid = threadIdx.x;
  int blk = blockIdx.x;
  int i0 = blk * 16;
  if (tid < 16) { su[tid] = U4[i0 + tid]; snl[tid] = NS[i0 + tid]; }
  __syncthreads();
  {
    int si = tid * SSTR;
    float4 ws = W4[si];
    float nss = NS[si];
#pragma unroll
    for (int r = 0; r < 16; ++r)
      sc[r][tid] = evalK(su[r], snl[r], ws, nss);
  }
  __syncthreads();
  double acc[16];
#pragma unroll
  for (int r = 0; r < 16; ++r) acc[r] = 0.0;
  for (int k = 0; k < MNY; ++k) {
    double g = Ginv[(size_t)k * MNY + tid];  // coalesced
#pragma unroll
    for (int r = 0; r < 16; ++r)
      acc[r] = fma((double)sc[r][k], g, acc[r]);   // LDS broadcast
  }
#pragma unroll
  for (int r = 0; r < 16; ++r)
    D[(size_t)(i0 + r) * MNY + tid] = (float)acc[r];
}

// ---------------- K1: big matvec q = K p (+eta p), p = z + beta p ----------------
extern "C" __global__ void __launch_bounds__(512, 4)
k_matvec(const float4* __restrict__ U4, const float4* __restrict__ W4,
         const float* __restrict__ NS,
         const float2* __restrict__ Zv, const float2* __restrict__ Pfp,
         float2* __restrict__ Pfc, float2* __restrict__ qpart,
         double* __restrict__ pqpart, const double* __restrict__ rhopart, int t)
{
  __shared__ float4 sw[JCH];
  __shared__ float4 sa[JCH];
  __shared__ double s1[512], s2[512];
  __shared__ double sc[2];
  int tid = threadIdx.x;
  int blk = blockIdx.x;
  int it = blk >> 4;
  int ch = blk & (NCH - 1);
  int j = ch * JCH + tid;

  float4 wj = W4[j];
  float nj = NS[j];
  float2 zj = Zv[j];
  float2 pj = Pfp[j];

  // beta = rho_{t-1} / rho_{t-2}
  if (t == 1) {
    if (tid < 2) sc[tid] = 0.0;
    __syncthreads();
  } else {
    const double* cur = rhopart + ((t - 1) & 1) * 128;
    const double* prv = rhopart + ((t - 2) & 1) * 128;
    if (tid < 128) { s1[tid] = cur[tid]; s2[tid] = prv[tid]; }
    __syncthreads();
    for (int st = 64; st >= 2; st >>= 1) {
      if (tid < st) { s1[tid] += s1[tid + st]; s2[tid] += s2[tid + st]; }
      __syncthreads();
    }
    if (tid < 2) sc[tid] = s1[tid] / s2[tid];
    __syncthreads();
  }
  float b0 = (float)sc[0], b1 = (float)sc[1];

  sw[tid] = wj;
  sa[tid] = make_float4(nj, fmaf(b0, pj.x, zj.x), fmaf(b1, pj.y, zj.y), 0.f);
  __syncthreads();

  int js = tid & (NJS - 1);
  int ig = tid >> 4;
  int i0 = it * ITILE + ig * IB;
  float4 ui[IB];
  float ni[IB];
#pragma unroll
  for (int k = 0; k < IB; ++k) { ui[k] = U4[i0 + k]; ni[k] = NS[i0 + k]; }
  float qa0[IB], qa1[IB];
#pragma unroll
  for (int k = 0; k < IB; ++k) { qa0[k] = 0.f; qa1[k] = 0.f; }
#pragma unroll 4
  for (int jj = 0; jj < JPT; ++jj) {
    int jl = jj * NJS + js;
    float4 w = sw[jl];
    float4 aa = sa[jl];
#pragma unroll
    for (int k = 0; k < IB; ++k) {
      float ttn = -(ni[k] + aa.x);
      ttn = fmaf(ui[k].x, w.x, ttn);
      ttn = fmaf(ui[k].y, w.y, ttn);
      ttn = fmaf(ui[k].z, w.z, ttn);
      ttn = fmaf(ui[k].w, w.w, ttn);
      float e = EXP2F(ttn);
      qa0[k] = fmaf(e, aa.y, qa0[k]);
      qa1[k] = fmaf(e, aa.z, qa1[k]);
    }
  }
#pragma unroll
  for (int k = 0; k < IB; ++k) {
#pragma unroll
    for (int d = 8; d >= 1; d >>= 1) {
      qa0[k] += __shfl_down(qa0[k], (unsigned)d, 16);
      qa1[k] += __shfl_down(qa1[k], (unsigned)d, 16);
    }
  }
  double pq0 = 0.0, pq1 = 0.0;
  if (js == 0) {
    int owner = (it & (NCH - 1));
#pragma unroll
    for (int k = 0; k < IB; ++k) {
      int i = i0 + k;
      float2 zi = Zv[i];
      float2 pi = Pfp[i];
      float pn0 = fmaf(b0, pi.x, zi.x);
      float pn1 = fmaf(b1, pi.y, zi.y);
      qpart[(size_t)ch * NPTS + i] = make_float2(qa0[k], qa1[k]);
      if (ch == owner) Pfc[i] = make_float2(pn0, pn1);
      pq0 += (double)pn0 * (double)qa0[k];
      pq1 += (double)pn1 * (double)qa1[k];
      if (ch == 0) {
        pq0 += NUG * (double)pn0 * (double)pn0;
        pq1 += NUG * (double)pn1 * (double)pn1;
      }
    }
  }
  s1[tid] = pq0;
  s2[tid] = pq1;
  __syncthreads();
  for (int st = 256; st >= 1; st >>= 1) {
    if (tid < st) { s1[tid] += s1[tid + st]; s2[tid] += s2[tid + st]; }
    __syncthreads();
  }
  if (tid == 0) { pqpart[blk * 2 + 0] = s1[0]; pqpart[blk * 2 + 1] = s2[0]; }
}

// ---------------- K2: alpha, x/r update, y1 = C^T r partials ----------------
extern "C" __global__ void __launch_bounds__(256)
k_update(const float* __restrict__ qpartf, const float2* __restrict__ Pfc,
         double* __restrict__ r64, double* __restrict__ x64,
         const float4* __restrict__ U4, const float4* __restrict__ W4,
         const float* __restrict__ NS,
         const double* __restrict__ pqpart, const double* __restrict__ rhopart,
         double* __restrict__ y1part, int t)
{
  __shared__ double s1[256];
  __shared__ double s2[128];
  __shared__ double alpha2[2];
  __shared__ float4 su[128];
  __shared__ float snl[128];
  __shared__ double rl[2][128];
  int tid = threadIdx.x;
  int blk = blockIdx.x;
  int idx = blk * 256 + tid;
  double rv;
  if (t > 0) {
    s1[tid] = pqpart[tid] + pqpart[tid + 256] + pqpart[tid + 512] + pqpart[tid + 768];
    if (tid < 128) s2[tid] = rhopart[((t - 1) & 1) * 128 + tid];
    __syncthreads();
    for (int st = 128; st >= 2; st >>= 1) {
      if (tid < st) s1[tid] += s1[tid + st];
      if (st <= 64 && tid < st) s2[tid] += s2[tid + st];
      __syncthreads();
    }
    if (tid < 2) alpha2[tid] = s2[tid] / s1[tid];
    __syncthreads();
    double a = alpha2[idx & 1];
    float pn = ((const float*)Pfc)[idx];
    double q = 0.0;
#pragma unroll
    for (int c = 0; c < NCH; ++c) q += (double)qpartf[(size_t)c * N2 + idx];
    q = fma((double)NUG, (double)pn, q);
    rv = fma(-a, q, r64[idx]);
    x64[idx] = fma(a, (double)pn, x64[idx]);
    r64[idx] = rv;
  } else {
    rv = r64[idx];
  }
  rl[idx & 1][tid >> 1] = rv;
  if (tid < 128) {
    su[tid] = U4[blk * 128 + tid];
    snl[tid] = NS[blk * 128 + tid];
  }
  __syncthreads();
  for (int rr = 0; rr < MNY / 256; ++rr) {
    int s = rr * 256 + tid;
    int si = s * SSTR;
    float4 ws = W4[si];
    float nss = NS[si];
    double y0 = 0.0, y1v = 0.0;
#pragma unroll 4
    for (int il = 0; il < 128; ++il) {
      float4 u = su[il];
      float tt = fmaf(u.x, ws.x, fmaf(u.y, ws.y, fmaf(u.z, ws.z, u.w * ws.w)));
      float e = EXP2F(tt - snl[il] - nss);
      y0 = fma((double)e, rl[0][il], y0);
      y1v = fma((double)e, rl[1][il], y1v);
    }
    y1part[(size_t)s * 128 + blk * 2 + 0] = y0;
    y1part[(size_t)s * 128 + blk * 2 + 1] = y1v;
  }
}

// ---------------- K3 (D path): z = (r - D y1)/eta ; rho partials ----------------
extern "C" __global__ void __launch_bounds__(256)
k_dz(const double* __restrict__ r64, const double* __restrict__ y1part,
     const float* __restrict__ D, float2* __restrict__ Zv,
     double* __restrict__ rhopart, int t)
{
  __shared__ double ly1[MNY][2];
  __shared__ double zl[128][2];
  __shared__ double s1[256], s2[256];
  int tid = threadIdx.x;
  int blk = blockIdx.x;
  for (int s = tid; s < MNY; s += 256) {
    const double* base = y1part + (size_t)s * 128;
    double a0 = 0.0, a1 = 0.0;
#pragma unroll 8
    for (int b = 0; b < 64; ++b) { a0 += base[2 * b]; a1 += base[2 * b + 1]; }
    ly1[s][0] = a0; ly1[s][1] = a1;
  }
  __syncthreads();
  {
    int lane = tid & 63, wv = tid >> 6;      // 4 waves
    for (int rnd = 0; rnd < 32; ++rnd) {
      int pt = wv * 32 + rnd;
      const float* drow = D + (size_t)(blk * 128 + pt) * MNY;
      double a0 = 0.0, a1 = 0.0;
#pragma unroll
      for (int m = 0; m < MNY / 64; ++m) {
        int s = lane + 64 * m;               // coalesced across lanes
        double dv = (double)drow[s];
        a0 = fma(dv, ly1[s][0], a0);
        a1 = fma(dv, ly1[s][1], a1);
      }
#pragma unroll
      for (int d = 32; d >= 1; d >>= 1) {
        a0 += __shfl_down(a0, (unsigned)d, 64);
        a1 += __shfl_down(a1, (unsigned)d, 64);
      }
      if (lane == 0) { zl[pt][0] = a0; zl[pt][1] = a1; }
    }
  }
  __syncthreads();
  double rz0 = 0.0, rz1 = 0.0;
  if (tid < 128) {
    int i = blk * 128 + tid;
    double r0 = r64[2 * i], r1 = r64[2 * i + 1];
    double z0 = (r0 - zl[tid][0]) * INVNUG;
    double z1 = (r1 - zl[tid][1]) * INVNUG;
    Zv[i] = make_float2((float)z0, (float)z1);
    rz0 = r0 * z0;
    rz1 = r1 * z1;
  }
  s1[tid] = rz0;
  s2[tid] = rz1;
  __syncthreads();
  for (int st = 128; st >= 1; st >>= 1) {
    if (tid < st) { s1[tid] += s1[tid + st]; s2[tid] += s2[tid + st]; }
    __syncthreads();
  }
  if (tid == 0) {
    rhopart[(t & 1) * 128 + blk * 2 + 0] = s1[0];
    rhopart[(t & 1) * 128 + blk * 2 + 1] = s2[0];
  }
}

// ---------------- K34 fallback (no-D path) ----------------
extern "C" __global__ void __launch_bounds__(256)
k_y2z(const float4* __restrict__ U4, const float4* __restrict__ W4,
      const float* __restrict__ NS, const double* __restrict__ r64,
      const double* __restrict__ y1part, const double* __restrict__ Ginv,
      float2* __restrict__ Zv, double* __restrict__ rhopart, int t)
{
  __shared__ double ly1[MNY][2];
  __shared__ double ly2[MNY][2];
  __shared__ double s1[256], s2[256];
  int tid = threadIdx.x;
  int blk = blockIdx.x;
  for (int s = tid; s < MNY; s += 256) {
    const double* base = y1part + (size_t)s * 128;
    double a0 = 0.0, a1 = 0.0;
#pragma unroll 8
    for (int b = 0; b < 64; ++b) { a0 += base[2 * b]; a1 += base[2 * b + 1]; }
    ly1[s][0] = a0; ly1[s][1] = a1;
  }
  __syncthreads();
  {
    int g = tid >> 5, l = tid & 31;
    for (int ss = 0; ss < MNY / 8; ++ss) {
      int so = g * (MNY / 8) + ss;
      const double* grow = Ginv + (size_t)so * MNY;
      double c0 = 0.0, c1 = 0.0;
#pragma unroll
      for (int m = 0; m < MNY / 32; ++m) {
        int jj = m * 32 + l;
        double gv = grow[jj];
        c0 = fma(gv, ly1[jj][0], c0);
        c1 = fma(gv, ly1[jj][1], c1);
      }
#pragma unroll
      for (int d = 16; d >= 1; d >>= 1) {
        c0 += __shfl_down(c0, (unsigned)d, 32);
        c1 += __shfl_down(c1, (unsigned)d, 32);
      }
      if (l == 0) { ly2[so][0] = c0; ly2[so][1] = c1; }
    }
  }
  __syncthreads();
  int pt = tid & 127;
  int half = tid >> 7;
  int i = blk * 128 + pt;
  float4 u = U4[i];
  float nu = NS[i];
  double acc0 = 0.0, acc1 = 0.0;
  int sbase = half * (MNY / 2);
#pragma unroll 4
  for (int s = 0; s < MNY / 2; ++s) {
    int so = sbase + s;
    int si = so * SSTR;
    float4 ws = W4[si];
    float nss = NS[si];
    float tt = fmaf(u.x, ws.x, fmaf(u.y, ws.y, fmaf(u.z, ws.z, u.w * ws.w)));
    float e = EXP2F(tt - nu - nss);
    acc0 = fma((double)e, ly2[so][0], acc0);
    acc1 = fma((double)e, ly2[so][1], acc1);
  }
  s1[tid] = acc0;
  s2[tid] = acc1;
  __syncthreads();
  double rz0 = 0.0, rz1 = 0.0;
  if (tid < 128) {
    double a0 = s1[tid] + s1[tid + 128];
    double a1 = s2[tid] + s2[tid + 128];
    double r0 = r64[2 * i], r1 = r64[2 * i + 1];
    double z0 = (r0 - a0) * INVNUG;
    double z1 = (r1 - a1) * INVNUG;
    Zv[i] = make_float2((float)z0, (float)z1);
    rz0 = r0 * z0;
    rz1 = r1 * z1;
  }
  __syncthreads();
  s1[tid] = rz0;
  s2[tid] = rz1;
  __syncthreads();
  for (int st = 128; st >= 1; st >>= 1) {
    if (tid < st) { s1[tid] += s1[tid + st]; s2[tid] += s2[tid + st]; }
    __syncthreads();
  }
  if (tid == 0) {
    rhopart[(t & 1) * 128 + blk * 2 + 0] = s1[0];
    rhopart[(t & 1) * 128 + blk * 2 + 1] = s2[0];
  }
}

// ---------------- final combine ----------------
extern "C" __global__ void __launch_bounds__(256)
k_final(const float* __restrict__ Z, const double* __restrict__ x64,
        const double* __restrict__ mmdpart, float* __restrict__ out)
{
  __shared__ double sred[256];
  int tid = threadIdx.x;
  double zx = 0.0;
  for (int idx = tid; idx < N2; idx += 256)
    zx += (double)Z[idx] * x64[idx];
  double acc[4];
  acc[0] = zx;
  acc[1] = mmdpart[tid * 3 + 0];
  acc[2] = mmdpart[tid * 3 + 1];
  acc[3] = mmdpart[tid * 3 + 2];
  double tot[4];
  for (int k = 0; k < 4; ++k) {
    sred[tid] = acc[k];
    __syncthreads();
    for (int st = 128; st >= 1; st >>= 1) {
      if (tid < st) sred[tid] += sred[tid + st];
      __syncthreads();
    }
    tot[k] = sred[0];
    __syncthreads();
  }
  if (tid == 0) {
    double nn = (double)NPTS * (double)NPTS;
    double mmd = (tot[1] - 2.0 * tot[2] + tot[3]) / nn;
    out[0] = (float)(mmd + LAM * tot[0]);
  }
}

extern "C" void kernel_launch(void* const* d_in, const int* in_sizes, int n_in,
                              void* d_out, int out_size, void* d_ws, size_t ws_size,
                              hipStream_t stream)
{
  (void)in_sizes; (void)n_in; (void)out_size;
  const float* Xmu  = (const float*)d_in[0];
  const float* Yeta = (const float*)d_in[1];
  const float* Ymu  = (const float*)d_in[2];
  const float* Z    = (const float*)d_in[3];
  float* out = (float*)d_out;

  char* w = (char*)d_ws;
  float4* U4      = (float4*)(w);                      // 128K
  float4* W4      = (float4*)(w + (128 << 10));        // 128K
  float*  NS      = (float*)(w + (256 << 10));         // 32K
  float4* M4      = (float4*)(w + (288 << 10));        // 128K
  float4* Y4      = (float4*)(w + (416 << 10));        // 128K
  float2* Zv      = (float2*)(w + (544 << 10));        // 64K
  float2* Pf[2]   = { (float2*)(w + (608 << 10)), (float2*)(w + (672 << 10)) };
  double* r64     = (double*)(w + (736 << 10));        // 128K
  double* x64     = (double*)(w + (864 << 10));        // 128K
  float2* qpart   = (float2*)(w + (992 << 10));        // 1M
  double* pqpart  = (double*)(w + (2016 << 10));       // 8K
  double* rhopart = (double*)(w + (2024 << 10));       // 2K
  double* y1part  = (double*)(w + (2026 << 10));       // 512K
  double* mmdpart = (double*)(w + (2546 << 10));       // 6K
  double* Gb0     = (double*)(w + (2552 << 10));       // 2M
  double* Gb1     = (double*)(w + (4600 << 10));       // 2M
  float*  D       = (float*)(w + (6656 << 10));        // 16M
  int useD = (ws_size >= ((size_t)(6656 + 16384) << 10)) ? 1 : 0;

  hipLaunchKernelGGL(k_setup, dim3(64), dim3(256), 0, stream,
                     Xmu, Yeta, Ymu, Z, U4, W4, NS, M4, Y4,
                     Pf[0], Pf[1], r64, x64);
  hipLaunchKernelGGL(k_mmd, dim3(256), dim3(MTPB), 0, stream, M4, Y4, mmdpart);
  hipLaunchKernelGGL(k_gbuild, dim3(256), dim3(256), 0, stream, U4, W4, NS, Gb0);
  for (int p = 0; p < MNY / 16; ++p) {       // 32 panel launches
    double* Mc = (p & 1) ? Gb1 : Gb0;
    double* Mn = (p & 1) ? Gb0 : Gb1;
    hipLaunchKernelGGL(k_gjpanel, dim3(64), dim3(512), 0, stream, Mc, Mn, p * 16);
  }
  double* Ginv = Gb0;                    // 32 panels: last write lands in Gb0
  if (useD)
    hipLaunchKernelGGL(k_dbuild, dim3(512), dim3(512), 0, stream,
                       U4, W4, NS, Ginv, D);

  // bootstrap: y1 = C^T r0; z0 = P r0; rho_0
  hipLaunchKernelGGL(k_update, dim3(64), dim3(256), 0, stream,
                     (const float*)qpart, Pf[0], r64, x64, U4, W4, NS,
                     pqpart, rhopart, y1part, 0);
  if (useD)
    hipLaunchKernelGGL(k_dz, dim3(64), dim3(256), 0, stream,
                       r64, y1part, D, Zv, rhopart, 0);
  else
    hipLaunchKernelGGL(k_y2z, dim3(64), dim3(256), 0, stream,
                       U4, W4, NS, r64, y1part, Ginv, Zv, rhopart, 0);

  for (int t = 1; t <= T_ITERS; ++t) {
    float2* Pprev = Pf[(t - 1) & 1];
    float2* Pcur  = Pf[t & 1];
    hipLaunchKernelGGL(k_matvec, dim3(NBLK1), dim3(512), 0, stream,
                       U4, W4, NS, Zv, Pprev, Pcur, qpart, pqpart, rhopart, t);
    hipLaunchKernelGGL(k_update, dim3(64), dim3(256), 0, stream,
                       (const float*)qpart, Pcur, r64, x64, U4, W4, NS,
                       pqpart, rhopart, y1part, t);
    if (t < T_ITERS) {
      if (useD)
        hipLaunchKernelGGL(k_dz, dim3(64), dim3(256), 0, stream,
                           r64, y1part, D, Zv, rhopart, t);
      else
        hipLaunchKernelGGL(k_y2z, dim3(64), dim3(256), 0, stream,
                           U4, W4, NS, r64, y1part, Ginv, Zv, rhopart, t);
    }
  }
  hipLaunchKernelGGL(k_final, dim3(1), dim3(256), 0, stream,
                     Z, x64, mmdpart, out);
}